// Round 1
// baseline (400.226 us; speedup 1.0000x reference)
//
#include <hip/hip_runtime.h>
#include <math.h>

#define N_NODES 10000
#define N_EDGES 50000
#define N_GRAPHS 8
#define IN_DIM  16
#define HID     64
#define EHID    32
#define NLAYER  3
#define NK      33
#define BN_EPS  1e-5f

// ---------------- workspace layout (float offsets) ----------------
#define OFF_H      0u          // N*H = 640000
#define OFF_H2     640000u
#define OFF_AGG    1280000u
#define OFF_U      1920000u
#define OFF_V      2560000u
#define OFF_ATAB   3200000u    // L*NK*4096 = 405504
#define OFF_CTAB   3605504u    // 405504
#define OFF_S      4011008u    // L*NK breakpoints (pad to 128)
#define OFF_NB     4011136u    // L ints (pad to 64)
#define OFF_DEG    4011200u    // N ints
#define OFF_INVDEG 4021200u    // N floats
#define OFF_STATS  4031200u    // chanSum[64] + chanSumSq[64]
#define OFF_GSUM   4031328u    // G*H = 512
#define OFF_GMAX   4031840u    // 512
#define OFF_GCNT   4032352u    // G ints

// in-degree of dst
__global__ void k_deg(const int* __restrict__ ei, int* __restrict__ deg) {
    int e = blockIdx.x * blockDim.x + threadIdx.x;
    if (e < N_EDGES) atomicAdd(&deg[ei[N_EDGES + e]], 1);
}

__global__ void k_invdeg(const int* __restrict__ deg, float* __restrict__ invdeg) {
    int n = blockIdx.x * blockDim.x + threadIdx.x;
    if (n < N_NODES) invdeg[n] = 1.0f / fmaxf((float)deg[n], 1.0f);
}

// h = x @ emb_w + emb_b   (wave = one node, lane = channel)
__global__ void k_embed(const float* __restrict__ x, const float* __restrict__ w,
                        const float* __restrict__ b, float* __restrict__ h) {
    int idx = blockIdx.x * blockDim.x + threadIdx.x;   // exact: 2500*256 = N*H
    int n = idx >> 6, o = idx & 63;
    const float* xr = x + n * IN_DIM;
    float acc = b[o];
    #pragma unroll
    for (int i = 0; i < IN_DIM; ++i) acc = fmaf(xr[i], w[i * HID + o], acc);
    h[idx] = acc;
}

// per-layer: collect & sort positive relu breakpoints t_j = -b_j/a_j
__global__ void k_s1(const float* __restrict__ e1w, const float* __restrict__ e1b,
                     float* __restrict__ s_arr, int* __restrict__ nb) {
    int l = blockIdx.x;
    if (threadIdx.x != 0) return;
    float t[EHID]; int c = 0;
    for (int j = 0; j < EHID; ++j) {
        float a = e1w[l * EHID + j], b = e1b[l * EHID + j];
        if ((a > 0.f && b < 0.f) || (a < 0.f && b > 0.f)) t[c++] = -b / a;
    }
    for (int i = 1; i < c; ++i) {            // insertion sort (<=32 elems)
        float v = t[i]; int j = i - 1;
        while (j >= 0 && t[j] > v) { t[j + 1] = t[j]; --j; }
        t[j + 1] = v;
    }
    for (int i = 0; i < c; ++i) s_arr[l * NK + i] = t[i];
    nb[l] = c;
}

// per (interval k, layer l): A_k = sum_j m_j a_j e2w[j], C_k = sum_j m_j b_j e2w[j] + e2b
__global__ void k_s2(const float* __restrict__ e1w, const float* __restrict__ e1b,
                     const float* __restrict__ e2w, const float* __restrict__ e2b,
                     const float* __restrict__ s_arr, const int* __restrict__ nb,
                     float* __restrict__ Atab, float* __restrict__ Ctab) {
    int k = blockIdx.x, l = blockIdx.y;
    int nbl = nb[l];
    if (k > nbl) return;
    __shared__ float sma[EHID], smb[EHID];
    if (threadIdx.x < EHID) {
        float a = e1w[l * EHID + threadIdx.x], b = e1b[l * EHID + threadIdx.x];
        float lo = (k == 0) ? 0.f : s_arr[l * NK + k - 1];
        float p  = (k == nbl) ? (lo + 1.0f) : 0.5f * (lo + s_arr[l * NK + k]);
        float m  = (p * a + b > 0.f) ? 1.f : 0.f;
        sma[threadIdx.x] = m * a;
        smb[threadIdx.x] = m * b;
    }
    __syncthreads();
    for (int idx = threadIdx.x; idx < HID * HID; idx += blockDim.x) {
        float accA = 0.f, accC = e2b[l * HID * HID + idx];
        #pragma unroll
        for (int j = 0; j < EHID; ++j) {
            float w = e2w[(l * EHID + j) * (HID * HID) + idx];
            accA = fmaf(sma[j], w, accA);
            accC = fmaf(smb[j], w, accC);
        }
        Atab[(l * NK + k) * (HID * HID) + idx] = accA;
        Ctab[(l * NK + k) * (HID * HID) + idx] = accC;
    }
}

// fast-path precompute (valid iff nb==0 -> single interval): U = h@A0, V = h@C0
__global__ void k_uv(const float* __restrict__ h, const float* __restrict__ Atab,
                     const float* __restrict__ Ctab, const int* __restrict__ nb,
                     float* __restrict__ U, float* __restrict__ V, int l) {
    if (nb[l] != 0) return;
    int idx = blockIdx.x * blockDim.x + threadIdx.x;
    int n = idx >> 6, o = idx & 63;
    const float* A = Atab + (l * NK) * (HID * HID);
    const float* C = Ctab + (l * NK) * (HID * HID);
    const float* hn = h + n * HID;
    float au = 0.f, cu = 0.f;
    #pragma unroll
    for (int i = 0; i < HID; ++i) {
        float hv = hn[i];
        au = fmaf(hv, A[i * HID + o], au);
        cu = fmaf(hv, C[i * HID + o], cu);
    }
    U[idx] = au; V[idx] = cu;
}

// one wave per edge: msg = ea*(h_src@A_k) + (h_src@C_k), scatter-add into agg[dst]
__global__ void k_msg(const int* __restrict__ ei, const float* __restrict__ h,
                      const float* __restrict__ U, const float* __restrict__ V,
                      const float* __restrict__ Atab, const float* __restrict__ Ctab,
                      const float* __restrict__ s_arr, const int* __restrict__ nbp,
                      float* __restrict__ agg, int l) {
    int wid = threadIdx.x >> 6, lane = threadIdx.x & 63;
    int e = blockIdx.x * 4 + wid;
    if (e >= N_EDGES) return;
    int src = ei[e], dst = ei[N_EDGES + e];
    const float* hs = h + src * HID;
    const float* hd = h + dst * HID;
    float d0 = hs[0] - hd[0], d1 = hs[1] - hd[1], d2 = hs[2] - hd[2];
    float ea = sqrtf(d0 * d0 + d1 * d1 + d2 * d2);
    int nb = nbp[l];
    float m;
    if (nb == 0) {
        int uidx = src * HID + lane;
        m = fmaf(ea, U[uidx], V[uidx]);
    } else {
        int k = 0;
        for (int i = 0; i < nb; ++i) k += (ea > s_arr[l * NK + i]) ? 1 : 0;
        const float* A = Atab + (l * NK + k) * (HID * HID);
        const float* C = Ctab + (l * NK + k) * (HID * HID);
        float au = 0.f, cu = 0.f;
        for (int i = 0; i < HID; ++i) {
            float hv = hs[i];
            au = fmaf(hv, A[i * HID + lane], au);
            cu = fmaf(hv, C[i * HID + lane], cu);
        }
        m = fmaf(ea, au, cu);
    }
    atomicAdd(&agg[dst * HID + lane], m);
}

// h2 = agg*invdeg + h@self_w + self_b ; accumulate per-channel sums
__global__ void k_h2sum(const float* __restrict__ agg, const float* __restrict__ invdeg,
                        const float* __restrict__ h, const float* __restrict__ sw,
                        const float* __restrict__ sb, float* __restrict__ h2,
                        float* __restrict__ chanSum, int l) {
    int idx = blockIdx.x * blockDim.x + threadIdx.x;   // exact N*H
    int n = idx >> 6, o = idx & 63;
    const float* swl = sw + l * HID * HID;
    const float* hn = h + n * HID;
    float acc = sb[l * HID + o];
    #pragma unroll
    for (int i = 0; i < HID; ++i) acc = fmaf(hn[i], swl[i * HID + o], acc);
    float v = fmaf(agg[idx], invdeg[n], acc);
    h2[idx] = v;
    __shared__ float sh[256];
    sh[threadIdx.x] = v;
    __syncthreads();
    if (threadIdx.x < HID) {
        float s = sh[threadIdx.x] + sh[threadIdx.x + 64] + sh[threadIdx.x + 128] + sh[threadIdx.x + 192];
        atomicAdd(&chanSum[threadIdx.x], s);
    }
}

// second pass: per-channel sum of (h2-mu)^2
__global__ void k_var(const float* __restrict__ h2, const float* __restrict__ chanSum,
                      float* __restrict__ chanSumSq) {
    int idx = blockIdx.x * blockDim.x + threadIdx.x;
    int o = idx & 63;
    float mu = chanSum[o] * (1.0f / N_NODES);
    float d = h2[idx] - mu;
    float v = d * d;
    __shared__ float sh[256];
    sh[threadIdx.x] = v;
    __syncthreads();
    if (threadIdx.x < HID) {
        float s = sh[threadIdx.x] + sh[threadIdx.x + 64] + sh[threadIdx.x + 128] + sh[threadIdx.x + 192];
        atomicAdd(&chanSumSq[threadIdx.x], s);
    }
}

// h = relu(g*(h2-mu)*rstd + b)
__global__ void k_bnrelu(const float* __restrict__ h2, const float* __restrict__ chanSum,
                         const float* __restrict__ chanSumSq, const float* __restrict__ g,
                         const float* __restrict__ b, float* __restrict__ h, int l) {
    int idx = blockIdx.x * blockDim.x + threadIdx.x;
    int o = idx & 63;
    float mu  = chanSum[o]   * (1.0f / N_NODES);
    float var = chanSumSq[o] * (1.0f / N_NODES);
    float rstd = 1.0f / sqrtf(var + BN_EPS);
    float v = fmaf(g[l * HID + o] * rstd, h2[idx] - mu, b[l * HID + o]);
    h[idx] = fmaxf(v, 0.f);
}

// segment mean/max pooling; batch is sorted -> run-length batching of atomics
__global__ void k_pool(const float* __restrict__ h, const int* __restrict__ batch,
                       float* __restrict__ gsum, float* __restrict__ gmax,
                       int* __restrict__ gcnt) {
    int wid = (blockIdx.x * blockDim.x + threadIdx.x) >> 6;
    int lane = threadIdx.x & 63;
    int n0 = wid * 40;
    int n1 = min(n0 + 40, N_NODES);
    float asum = 0.f, amax = 0.f;
    int cb = -1, run = 0;
    for (int n = n0; n < n1; ++n) {
        int b = batch[n];
        float v = h[n * HID + lane];
        if (b != cb) {
            if (cb >= 0) {
                atomicAdd(&gsum[cb * HID + lane], asum);
                atomicMax((int*)&gmax[cb * HID + lane], __float_as_int(amax));
                if (lane == 0) atomicAdd(&gcnt[cb], run);
            }
            cb = b; asum = v; amax = v; run = 1;
        } else {
            asum += v; amax = fmaxf(amax, v); ++run;
        }
    }
    if (cb >= 0) {
        atomicAdd(&gsum[cb * HID + lane], asum);
        atomicMax((int*)&gmax[cb * HID + lane], __float_as_int(amax));
        if (lane == 0) atomicAdd(&gcnt[cb], run);
    }
}

// classifier: sigmoid([mean | max] @ cls_w + cls_b)
__global__ void k_cls(const float* __restrict__ gsum, const float* __restrict__ gmax,
                      const int* __restrict__ gcnt, const float* __restrict__ cw,
                      const float* __restrict__ cb, float* __restrict__ out) {
    int g = threadIdx.x;
    if (g >= N_GRAPHS) return;
    float cnt = fmaxf((float)gcnt[g], 1.0f);
    float acc = cb[0];
    for (int o = 0; o < HID; ++o) acc = fmaf(gsum[g * HID + o] / cnt, cw[o], acc);
    for (int o = 0; o < HID; ++o) acc = fmaf(gmax[g * HID + o], cw[HID + o], acc);
    out[g] = 1.0f / (1.0f + expf(-acc));
}

extern "C" void kernel_launch(void* const* d_in, const int* in_sizes, int n_in,
                              void* d_out, int out_size, void* d_ws, size_t ws_size,
                              hipStream_t stream) {
    const float* x      = (const float*)d_in[0];
    const int*   ei     = (const int*)  d_in[1];
    const int*   batch  = (const int*)  d_in[2];
    const float* emb_w  = (const float*)d_in[3];
    const float* emb_b  = (const float*)d_in[4];
    const float* e1_w   = (const float*)d_in[5];
    const float* e1_b   = (const float*)d_in[6];
    const float* e2_w   = (const float*)d_in[7];
    const float* e2_b   = (const float*)d_in[8];
    const float* self_w = (const float*)d_in[9];
    const float* self_b = (const float*)d_in[10];
    const float* bn_g   = (const float*)d_in[11];
    const float* bn_b   = (const float*)d_in[12];
    const float* cls_w  = (const float*)d_in[13];
    const float* cls_b  = (const float*)d_in[14];
    float* out = (float*)d_out;

    float* wsf = (float*)d_ws;
    float* h      = wsf + OFF_H;
    float* h2     = wsf + OFF_H2;
    float* agg    = wsf + OFF_AGG;
    float* U      = wsf + OFF_U;
    float* V      = wsf + OFF_V;
    float* Atab   = wsf + OFF_ATAB;
    float* Ctab   = wsf + OFF_CTAB;
    float* s_arr  = wsf + OFF_S;
    int*   nb     = (int*)(wsf + OFF_NB);
    int*   deg    = (int*)(wsf + OFF_DEG);
    float* invdeg = wsf + OFF_INVDEG;
    float* chanSum   = wsf + OFF_STATS;
    float* chanSumSq = wsf + OFF_STATS + 64;
    float* gsum   = wsf + OFF_GSUM;
    float* gmax   = wsf + OFF_GMAX;
    int*   gcnt   = (int*)(wsf + OFF_GCNT);

    // degree + embedding + interval tables (weights-only precompute)
    hipMemsetAsync(deg, 0, N_NODES * sizeof(int), stream);
    k_deg<<<(N_EDGES + 255) / 256, 256, 0, stream>>>(ei, deg);
    k_invdeg<<<(N_NODES + 255) / 256, 256, 0, stream>>>(deg, invdeg);
    k_embed<<<(N_NODES * HID) / 256, 256, 0, stream>>>(x, emb_w, emb_b, h);
    k_s1<<<NLAYER, 32, 0, stream>>>(e1_w, e1_b, s_arr, nb);
    k_s2<<<dim3(NK, NLAYER), 256, 0, stream>>>(e1_w, e1_b, e2_w, e2_b, s_arr, nb, Atab, Ctab);

    for (int l = 0; l < NLAYER; ++l) {
        hipMemsetAsync(agg, 0, N_NODES * HID * sizeof(float), stream);
        hipMemsetAsync(chanSum, 0, 128 * sizeof(float), stream);
        k_uv<<<(N_NODES * HID) / 256, 256, 0, stream>>>(h, Atab, Ctab, nb, U, V, l);
        k_msg<<<(N_EDGES + 3) / 4, 256, 0, stream>>>(ei, h, U, V, Atab, Ctab, s_arr, nb, agg, l);
        k_h2sum<<<(N_NODES * HID) / 256, 256, 0, stream>>>(agg, invdeg, h, self_w, self_b, h2, chanSum, l);
        k_var<<<(N_NODES * HID) / 256, 256, 0, stream>>>(h2, chanSum, chanSumSq);
        k_bnrelu<<<(N_NODES * HID) / 256, 256, 0, stream>>>(h2, chanSum, chanSumSq, bn_g, bn_b, h, l);
    }

    // pooling + classifier
    hipMemsetAsync(gsum, 0, (2 * N_GRAPHS * HID + N_GRAPHS) * sizeof(float), stream);
    k_pool<<<63, 256, 0, stream>>>(h, batch, gsum, gmax, gcnt);
    k_cls<<<1, 64, 0, stream>>>(gsum, gmax, gcnt, cls_w, cls_b, out);
}